// Round 1
// baseline (300.499 us; speedup 1.0000x reference)
//
#include <hip/hip_runtime.h>
#include <math.h>

#define Bb   16
#define Ll   2048
#define Dd   1024
#define OSo  64
#define NCc  256
#define LABh 1024
#define BN_EPS 1e-5f

// ---------------------------------------------------------------------------
// K1: St[b][o][l] = sum_d X[b][l][d] * a_w[d][o] + a_b[o]   (transposed out)
// grid = 512 blocks (16 b * 32 l-tiles), 256 threads, 64x64 tile, Kc=32
// ---------------------------------------------------------------------------
__global__ __launch_bounds__(256) void k1_score(const float* __restrict__ X,
                                                const float* __restrict__ a_w,
                                                const float* __restrict__ a_b,
                                                float* __restrict__ St) {
    __shared__ float As[32][68];   // [k][m=l]
    __shared__ float Bs[32][68];   // [k][n=o]
    __shared__ float Ts[64][65];   // [l][o] epilogue transpose
    const int tid = threadIdx.x;
    const int tx = tid & 15, ty = tid >> 4;
    const int mt = blockIdx.x;
    const int b  = mt >> 5;
    const int l0 = (mt & 31) << 6;
    const float* Arow = X + (size_t)(b * Ll + l0) * Dd;
    float acc[4][4] = {};
    for (int k0 = 0; k0 < Dd; k0 += 32) {
        #pragma unroll
        for (int i = 0; i < 8; ++i) {
            int idx = i * 256 + tid;
            int m = idx >> 5, k = idx & 31;
            As[k][m] = Arow[(size_t)m * Dd + k0 + k];
        }
        #pragma unroll
        for (int i = 0; i < 8; ++i) {
            int idx = i * 256 + tid;
            int k = idx >> 6, n = idx & 63;
            Bs[k][n] = a_w[(size_t)(k0 + k) * OSo + n];
        }
        __syncthreads();
        #pragma unroll
        for (int k = 0; k < 32; ++k) {
            float4 a4 = *(const float4*)&As[k][ty * 4];
            float4 b4 = *(const float4*)&Bs[k][tx * 4];
            float av[4] = {a4.x, a4.y, a4.z, a4.w};
            float bv[4] = {b4.x, b4.y, b4.z, b4.w};
            #pragma unroll
            for (int i = 0; i < 4; ++i)
                #pragma unroll
                for (int j = 0; j < 4; ++j) acc[i][j] += av[i] * bv[j];
        }
        __syncthreads();
    }
    #pragma unroll
    for (int i = 0; i < 4; ++i)
        #pragma unroll
        for (int j = 0; j < 4; ++j) Ts[ty * 4 + i][tx * 4 + j] = acc[i][j];
    __syncthreads();
    #pragma unroll
    for (int i = 0; i < 16; ++i) {
        int idx = i * 256 + tid;
        int o = idx >> 6, l = idx & 63;
        St[(size_t)(b * OSo + o) * Ll + l0 + l] = Ts[l][o] + a_b[o];
    }
}

// ---------------------------------------------------------------------------
// K2: in-place softmax over each row of length L  (rows = B*OS = 1024)
// ---------------------------------------------------------------------------
__global__ __launch_bounds__(256) void k2_softmax(float* __restrict__ St) {
    __shared__ float row[Ll];
    __shared__ float red[8];
    float* p = St + (size_t)blockIdx.x * Ll;
    const int tid = threadIdx.x;
    const int wave = tid >> 6, lane = tid & 63;
    float m = -1e30f;
    for (int i = tid; i < Ll; i += 256) { float v = p[i]; row[i] = v; m = fmaxf(m, v); }
    #pragma unroll
    for (int off = 32; off; off >>= 1) m = fmaxf(m, __shfl_down(m, off));
    if (lane == 0) red[wave] = m;
    __syncthreads();
    if (tid == 0) red[4] = fmaxf(fmaxf(red[0], red[1]), fmaxf(red[2], red[3]));
    __syncthreads();
    const float M = red[4];
    float s = 0.f;
    for (int i = tid; i < Ll; i += 256) { float e = __expf(row[i] - M); row[i] = e; s += e; }
    __syncthreads();   // ensure all reads of red[4] done before reuse
    #pragma unroll
    for (int off = 32; off; off >>= 1) s += __shfl_down(s, off);
    if (lane == 0) red[wave] = s;
    __syncthreads();
    if (tid == 0) red[4] = 1.f / (red[0] + red[1] + red[2] + red[3]);
    __syncthreads();
    const float inv = red[4];
    for (int i = tid; i < Ll; i += 256) p[i] = row[i] * inv;
}

// ---------------------------------------------------------------------------
// K3: Xp[b][o][d] = sum_l alpha[b][o][l] * X[b][l][d]
// grid = (16 d-tiles, 16 b), 64x64 tile, K = L = 2048
// ---------------------------------------------------------------------------
__global__ __launch_bounds__(256) void k3_pool(const float* __restrict__ alpha,
                                               const float* __restrict__ X,
                                               float* __restrict__ Xp) {
    __shared__ float As[32][68];   // [k=l][m=o]
    __shared__ float Bs[32][68];   // [k=l][n=d]
    __shared__ float Ts[64][65];
    const int tid = threadIdx.x;
    const int tx = tid & 15, ty = tid >> 4;
    const int b  = blockIdx.y;
    const int d0 = blockIdx.x << 6;
    const float* Ab = alpha + (size_t)b * OSo * Ll;
    const float* Xb = X + (size_t)b * Ll * Dd;
    float acc[4][4] = {};
    for (int k0 = 0; k0 < Ll; k0 += 32) {
        #pragma unroll
        for (int i = 0; i < 8; ++i) {
            int idx = i * 256 + tid;
            int m = idx >> 5, k = idx & 31;
            As[k][m] = Ab[(size_t)m * Ll + k0 + k];
        }
        #pragma unroll
        for (int i = 0; i < 8; ++i) {
            int idx = i * 256 + tid;
            int k = idx >> 6, n = idx & 63;
            Bs[k][n] = Xb[(size_t)(k0 + k) * Dd + d0 + n];
        }
        __syncthreads();
        #pragma unroll
        for (int k = 0; k < 32; ++k) {
            float4 a4 = *(const float4*)&As[k][ty * 4];
            float4 b4 = *(const float4*)&Bs[k][tx * 4];
            float av[4] = {a4.x, a4.y, a4.z, a4.w};
            float bv[4] = {b4.x, b4.y, b4.z, b4.w};
            #pragma unroll
            for (int i = 0; i < 4; ++i)
                #pragma unroll
                for (int j = 0; j < 4; ++j) acc[i][j] += av[i] * bv[j];
        }
        __syncthreads();
    }
    #pragma unroll
    for (int i = 0; i < 4; ++i)
        #pragma unroll
        for (int j = 0; j < 4; ++j) Ts[ty * 4 + i][tx * 4 + j] = acc[i][j];
    __syncthreads();
    #pragma unroll
    for (int i = 0; i < 16; ++i) {
        int idx = i * 256 + tid;
        int o = idx >> 6, d = idx & 63;
        Xp[(size_t)(b * OSo + o) * Dd + d0 + d] = Ts[o][d];
    }
}

// ---------------------------------------------------------------------------
// K4: Xh[m][h] = relu( ((Xp@h_w)[m][h] + h_b[h] - mean[h])*g/sqrt(var+eps) + beta[h] )
// m in [0, B*OS). grid = (16 h-tiles, 16 m-tiles)
// ---------------------------------------------------------------------------
__global__ __launch_bounds__(256) void k4_hidden(const float* __restrict__ Xp,
                                                 const float* __restrict__ h_w,
                                                 const float* __restrict__ h_b,
                                                 const float* __restrict__ gamma,
                                                 const float* __restrict__ beta,
                                                 const float* __restrict__ mean,
                                                 const float* __restrict__ var,
                                                 float* __restrict__ Xh) {
    __shared__ float As[32][68];
    __shared__ float Bs[32][68];
    __shared__ float Ts[64][65];
    const int tid = threadIdx.x;
    const int tx = tid & 15, ty = tid >> 4;
    const int m0 = blockIdx.y << 6;
    const int h0 = blockIdx.x << 6;
    float acc[4][4] = {};
    for (int k0 = 0; k0 < Dd; k0 += 32) {
        #pragma unroll
        for (int i = 0; i < 8; ++i) {
            int idx = i * 256 + tid;
            int m = idx >> 5, k = idx & 31;
            As[k][m] = Xp[(size_t)(m0 + m) * Dd + k0 + k];
        }
        #pragma unroll
        for (int i = 0; i < 8; ++i) {
            int idx = i * 256 + tid;
            int k = idx >> 6, n = idx & 63;
            Bs[k][n] = h_w[(size_t)(k0 + k) * LABh + h0 + n];
        }
        __syncthreads();
        #pragma unroll
        for (int k = 0; k < 32; ++k) {
            float4 a4 = *(const float4*)&As[k][ty * 4];
            float4 b4 = *(const float4*)&Bs[k][tx * 4];
            float av[4] = {a4.x, a4.y, a4.z, a4.w};
            float bv[4] = {b4.x, b4.y, b4.z, b4.w};
            #pragma unroll
            for (int i = 0; i < 4; ++i)
                #pragma unroll
                for (int j = 0; j < 4; ++j) acc[i][j] += av[i] * bv[j];
        }
        __syncthreads();
    }
    #pragma unroll
    for (int j = 0; j < 4; ++j) {
        int h = h0 + tx * 4 + j;
        float s   = gamma[h] * rsqrtf(var[h] + BN_EPS);
        float off = (h_b[h] - mean[h]) * s + beta[h];
        #pragma unroll
        for (int i = 0; i < 4; ++i)
            Ts[ty * 4 + i][tx * 4 + j] = fmaxf(0.f, acc[i][j] * s + off);
    }
    __syncthreads();
    #pragma unroll
    for (int i = 0; i < 16; ++i) {
        int idx = i * 256 + tid;
        int mm = idx >> 6, hh = idx & 63;
        Xh[(size_t)(m0 + mm) * LABh + h0 + hh] = Ts[mm][hh];
    }
}

// ---------------------------------------------------------------------------
// K5: sc[b][c][o] = sum_h labDesc[cand[b][c]][h] * Xh[b][o][h]
// grid = (4 c-tiles, 16 b), 64(c) x 64(o) tile, K = LAB
// ---------------------------------------------------------------------------
__global__ __launch_bounds__(256) void k5_scores(const int* __restrict__ cand,
                                                 const float* __restrict__ labDesc,
                                                 const float* __restrict__ Xh,
                                                 float* __restrict__ sc) {
    __shared__ float As[32][68];   // [k=h][m=c]
    __shared__ float Bs[32][68];   // [k=h][n=o]
    __shared__ float Ts[64][65];
    __shared__ int cidx[64];
    const int tid = threadIdx.x;
    const int tx = tid & 15, ty = tid >> 4;
    const int b  = blockIdx.y;
    const int c0 = blockIdx.x << 6;
    if (tid < 64) cidx[tid] = cand[b * NCc + c0 + tid];
    __syncthreads();
    const float* Xb = Xh + (size_t)b * OSo * LABh;
    float acc[4][4] = {};
    for (int k0 = 0; k0 < LABh; k0 += 32) {
        #pragma unroll
        for (int i = 0; i < 8; ++i) {
            int idx = i * 256 + tid;
            int m = idx >> 5, k = idx & 31;
            As[k][m] = labDesc[(size_t)cidx[m] * LABh + k0 + k];
        }
        #pragma unroll
        for (int i = 0; i < 8; ++i) {
            int idx = i * 256 + tid;
            int m = idx >> 5, k = idx & 31;
            Bs[k][m] = Xb[(size_t)m * LABh + k0 + k];
        }
        __syncthreads();
        #pragma unroll
        for (int k = 0; k < 32; ++k) {
            float4 a4 = *(const float4*)&As[k][ty * 4];
            float4 b4 = *(const float4*)&Bs[k][tx * 4];
            float av[4] = {a4.x, a4.y, a4.z, a4.w};
            float bv[4] = {b4.x, b4.y, b4.z, b4.w};
            #pragma unroll
            for (int i = 0; i < 4; ++i)
                #pragma unroll
                for (int j = 0; j < 4; ++j) acc[i][j] += av[i] * bv[j];
        }
        __syncthreads();
    }
    #pragma unroll
    for (int i = 0; i < 4; ++i)
        #pragma unroll
        for (int j = 0; j < 4; ++j) Ts[ty * 4 + i][tx * 4 + j] = acc[i][j];
    __syncthreads();
    #pragma unroll
    for (int i = 0; i < 16; ++i) {
        int idx = i * 256 + tid;
        int cc = idx >> 6, oo = idx & 63;
        sc[(size_t)(b * NCc + c0 + cc) * OSo + oo] = Ts[cc][oo];
    }
}

// ---------------------------------------------------------------------------
// K6: alpha2 = softmax over o (per b,c), out[b][c][h] = sum_o alpha2 * Xh[b][o][h]
// grid = (16 c-tiles-of-16, 16 b), 256 threads
// ---------------------------------------------------------------------------
__global__ __launch_bounds__(256) void k6_out(const float* __restrict__ sc,
                                              const float* __restrict__ Xh,
                                              float* __restrict__ out) {
    __shared__ float al[16][64];
    const int tid = threadIdx.x;
    const int b  = blockIdx.y;
    const int c0 = blockIdx.x << 4;
    // phase A: softmax over OS=64 for 16 candidate rows (16 threads each)
    {
        const int cl = tid >> 4, t16 = tid & 15;
        const float* srow = sc + (size_t)(b * NCc + c0 + cl) * OSo;
        float v[4];
        float m = -1e30f;
        #pragma unroll
        for (int j = 0; j < 4; ++j) { v[j] = srow[t16 + j * 16]; m = fmaxf(m, v[j]); }
        #pragma unroll
        for (int off = 8; off; off >>= 1) m = fmaxf(m, __shfl_xor(m, off, 16));
        float s = 0.f;
        #pragma unroll
        for (int j = 0; j < 4; ++j) { v[j] = __expf(v[j] - m); s += v[j]; }
        #pragma unroll
        for (int off = 8; off; off >>= 1) s += __shfl_xor(s, off, 16);
        float inv = 1.f / s;
        #pragma unroll
        for (int j = 0; j < 4; ++j) al[cl][t16 + j * 16] = v[j] * inv;
    }
    __syncthreads();
    // phase B: out rows = weighted sums of Xh rows
    const float* xb = Xh + (size_t)b * OSo * LABh;
    float acc[16][4] = {};
    for (int o = 0; o < OSo; ++o) {
        float xv[4];
        #pragma unroll
        for (int j = 0; j < 4; ++j) xv[j] = xb[(size_t)o * LABh + tid + j * 256];
        #pragma unroll
        for (int c = 0; c < 16; ++c) {
            float w = al[c][o];
            #pragma unroll
            for (int j = 0; j < 4; ++j) acc[c][j] += w * xv[j];
        }
    }
    #pragma unroll
    for (int c = 0; c < 16; ++c)
        #pragma unroll
        for (int j = 0; j < 4; ++j)
            out[(size_t)(b * NCc + c0 + c) * LABh + tid + j * 256] = acc[c][j];
}

// ---------------------------------------------------------------------------
extern "C" void kernel_launch(void* const* d_in, const int* in_sizes, int n_in,
                              void* d_out, int out_size, void* d_ws, size_t ws_size,
                              hipStream_t stream) {
    (void)in_sizes; (void)n_in; (void)out_size; (void)ws_size;
    const float* X      = (const float*)d_in[0];
    const int*   cand   = (const int*)  d_in[1];
    const float* a_w    = (const float*)d_in[2];
    const float* a_b    = (const float*)d_in[3];
    const float* h_w    = (const float*)d_in[4];
    const float* h_b    = (const float*)d_in[5];
    const float* gamma  = (const float*)d_in[6];
    const float* beta   = (const float*)d_in[7];
    const float* mean   = (const float*)d_in[8];
    const float* var    = (const float*)d_in[9];
    const float* labDesc= (const float*)d_in[10];
    float* outp = (float*)d_out;

    float* St = (float*)d_ws;                          // B*OS*L   = 2,097,152 f
    float* Xp = St + (size_t)Bb * OSo * Ll;            // B*OS*D   = 1,048,576 f
    float* Xh = Xp + (size_t)Bb * OSo * Dd;            // B*OS*LAB = 1,048,576 f
    float* sc = Xh + (size_t)Bb * OSo * LABh;          // B*NC*OS  =   262,144 f

    k1_score <<<dim3(512),     256, 0, stream>>>(X, a_w, a_b, St);
    k2_softmax<<<dim3(Bb * OSo), 256, 0, stream>>>(St);
    k3_pool  <<<dim3(16, Bb),  256, 0, stream>>>(St, X, Xp);
    k4_hidden<<<dim3(16, 16),  256, 0, stream>>>(Xp, h_w, h_b, gamma, beta, mean, var, Xh);
    k5_scores<<<dim3(4, Bb),   256, 0, stream>>>(cand, labDesc, Xh, sc);
    k6_out   <<<dim3(16, Bb),  256, 0, stream>>>(sc, Xh, outp);
}

// Round 2
// 143.143 us; speedup vs baseline: 2.0993x; 2.0993x over previous
//
#include <hip/hip_runtime.h>
#include <math.h>

#define Bb   16
#define Ll   2048
#define Dd   1024
#define OSo  64
#define NCc  256
#define LABh 1024
#define BN_EPS 1e-5f

typedef short s8v  __attribute__((ext_vector_type(8)));   // 8 bf16 = 4 VGPR
typedef short s4v  __attribute__((ext_vector_type(4)));
typedef float f32x4 __attribute__((ext_vector_type(4)));

__device__ __forceinline__ short f2b(float f) {           // f32 -> bf16 RNE
    union { float f; unsigned u; } v; v.f = f;
    unsigned r = (v.u + 0x7fffu + ((v.u >> 16) & 1u)) >> 16;
    return (short)r;
}
__device__ __forceinline__ float b2f(short s) {
    union { unsigned u; float f; } v; v.u = ((unsigned)(unsigned short)s) << 16;
    return v.f;
}
// swizzled short-index into a [rows][64] bf16 LDS tile (row stride 128B).
// byte ^= ((row&7)<<4) spreads the 128B-stride rows across banks (G4).
__device__ __forceinline__ int swi(int row, int kElem) {
    return (row * 128 + ((kElem * 2) ^ ((row & 7) << 4))) >> 1;
}
__device__ __forceinline__ f32x4 MF(s8v a, s8v b, f32x4 c) {
    return __builtin_amdgcn_mfma_f32_16x16x32_bf16(a, b, c, 0, 0, 0);
}

// ---------------------------------------------------------------------------
// k0: transpose+convert weights.  id<256: h_w[1024][1024] -> h_wT bf16[1024][1024]
//     id>=256: a_w[1024][64] -> a_wT bf16[64][1024]
// ---------------------------------------------------------------------------
__global__ __launch_bounds__(256) void k0(const float* __restrict__ h_w,
                                          const float* __restrict__ a_w,
                                          short* __restrict__ h_wT,
                                          short* __restrict__ a_wT) {
    __shared__ float t[64][68];
    const int tid = threadIdx.x, id = blockIdx.x;
    const float* src; short* dst; int srw, d0, y0;
    if (id < 256) { src = h_w; dst = h_wT; srw = LABh; d0 = (id & 15) * 64; y0 = (id >> 4) * 64; }
    else          { src = a_w; dst = a_wT; srw = OSo;  d0 = (id - 256) * 64; y0 = 0; }
    const int r = tid >> 2, cofs = (tid & 3) * 16;
    #pragma unroll
    for (int w = 0; w < 4; ++w) {
        float4 v = *(const float4*)&src[(size_t)(d0 + r) * srw + y0 + cofs + w * 4];
        t[r][cofs + w * 4 + 0] = v.x;
        t[r][cofs + w * 4 + 1] = v.y;
        t[r][cofs + w * 4 + 2] = v.z;
        t[r][cofs + w * 4 + 3] = v.w;
    }
    __syncthreads();
    s8v o0, o1;
    #pragma unroll
    for (int e = 0; e < 8; ++e) { o0[e] = f2b(t[cofs + e][r]); o1[e] = f2b(t[cofs + 8 + e][r]); }
    *(s8v*)&dst[(size_t)(y0 + r) * Dd + d0 + cofs]     = o0;
    *(s8v*)&dst[(size_t)(y0 + r) * Dd + d0 + cofs + 8] = o1;
}

// ---------------------------------------------------------------------------
// k1: St[b][o][l] = X@a_w + a_b  via bf16 MFMA.  tile 128(l) x 64(o), K=1024
// grid (16 ltiles, 16 b), 4 waves (2x2), wave tile 64x32
// ---------------------------------------------------------------------------
__global__ __launch_bounds__(256) void k1(const float* __restrict__ X,
                                          const short* __restrict__ a_wT,
                                          const float* __restrict__ a_b,
                                          float* __restrict__ St) {
    __shared__ __align__(16) float ts[128][65];            // 33.3KB; aliased below
    short* As = (short*)&ts[0][0];                          // [128][64] swizzled bf16
    short* Bs = As + 128 * 64;                              // [64][64]  swizzled bf16
    const int tid = threadIdx.x;
    const int lane = tid & 63, wave = tid >> 6;
    const int wm = wave >> 1, wn = wave & 1;
    const int b = blockIdx.y, l0 = blockIdx.x * 128;
    const float* Xb = X + ((size_t)b * Ll + l0) * Dd;
    f32x4 acc[4][2] = {};
    const int ar = tid >> 1, ak = (tid & 1) * 32;
    const int br = tid >> 2, bk = (tid & 3) * 16;
    for (int k0 = 0; k0 < Dd; k0 += 64) {
        #pragma unroll
        for (int w = 0; w < 4; ++w) {                       // stage A: X f32->bf16
            float4 v0 = *(const float4*)&Xb[(size_t)ar * Dd + k0 + ak + w * 8];
            float4 v1 = *(const float4*)&Xb[(size_t)ar * Dd + k0 + ak + w * 8 + 4];
            s8v s;
            s[0]=f2b(v0.x); s[1]=f2b(v0.y); s[2]=f2b(v0.z); s[3]=f2b(v0.w);
            s[4]=f2b(v1.x); s[5]=f2b(v1.y); s[6]=f2b(v1.z); s[7]=f2b(v1.w);
            *(s8v*)&As[swi(ar, ak + w * 8)] = s;
        }
        #pragma unroll
        for (int w = 0; w < 2; ++w)                         // stage B: a_wT bf16
            *(s8v*)&Bs[swi(br, bk + w * 8)] = *(const s8v*)&a_wT[(size_t)br * Dd + k0 + bk + w * 8];
        __syncthreads();
        #pragma unroll
        for (int kk = 0; kk < 2; ++kk) {
            const int kb = kk * 32 + (lane >> 4) * 8;
            s8v a[4], bb[2];
            #pragma unroll
            for (int i = 0; i < 4; ++i)
                a[i] = *(const s8v*)&As[swi(wm * 64 + i * 16 + (lane & 15), kb)];
            #pragma unroll
            for (int j = 0; j < 2; ++j)
                bb[j] = *(const s8v*)&Bs[swi(wn * 32 + j * 16 + (lane & 15), kb)];
            #pragma unroll
            for (int i = 0; i < 4; ++i)
                #pragma unroll
                for (int j = 0; j < 2; ++j)
                    acc[i][j] = MF(a[i], bb[j], acc[i][j]);
        }
        __syncthreads();
    }
    // epilogue: transpose via LDS -> St[o][l] rows
    #pragma unroll
    for (int i = 0; i < 4; ++i)
        #pragma unroll
        for (int j = 0; j < 2; ++j)
            #pragma unroll
            for (int r = 0; r < 4; ++r)
                ts[wm * 64 + i * 16 + (lane >> 4) * 4 + r][wn * 32 + j * 16 + (lane & 15)] = acc[i][j][r];
    __syncthreads();
    const int o = tid >> 2, lofs = (tid & 3) * 32;
    const float bias = a_b[o];
    float* Sp = St + ((size_t)b * OSo + o) * Ll + l0 + lofs;
    #pragma unroll
    for (int w = 0; w < 8; ++w) {
        float4 v;
        v.x = ts[lofs + w * 4 + 0][o] + bias;
        v.y = ts[lofs + w * 4 + 1][o] + bias;
        v.z = ts[lofs + w * 4 + 2][o] + bias;
        v.w = ts[lofs + w * 4 + 3][o] + bias;
        *(float4*)&Sp[w * 4] = v;
    }
}

// ---------------------------------------------------------------------------
// k2: softmax over L per (b,o) row; St f32 in -> alpha bf16 out
// ---------------------------------------------------------------------------
__global__ __launch_bounds__(256) void k2(const float* __restrict__ St, short* __restrict__ aBf) {
    __shared__ float row[Ll];
    __shared__ float red[8];
    const float* p = St + (size_t)blockIdx.x * Ll;
    short* ab = aBf + (size_t)blockIdx.x * Ll;
    const int tid = threadIdx.x;
    const int wave = tid >> 6, lane = tid & 63;
    float m = -1e30f;
    for (int i = tid; i < Ll; i += 256) { float v = p[i]; row[i] = v; m = fmaxf(m, v); }
    #pragma unroll
    for (int off = 32; off; off >>= 1) m = fmaxf(m, __shfl_down(m, off));
    if (lane == 0) red[wave] = m;
    __syncthreads();
    if (tid == 0) red[4] = fmaxf(fmaxf(red[0], red[1]), fmaxf(red[2], red[3]));
    __syncthreads();
    const float M = red[4];
    float s = 0.f;
    for (int i = tid; i < Ll; i += 256) { float e = __expf(row[i] - M); row[i] = e; s += e; }
    __syncthreads();
    #pragma unroll
    for (int off = 32; off; off >>= 1) s += __shfl_down(s, off);
    if (lane == 0) red[wave] = s;
    __syncthreads();
    if (tid == 0) red[4] = 1.f / (red[0] + red[1] + red[2] + red[3]);
    __syncthreads();
    const float inv = red[4];
    for (int i = tid; i < Ll; i += 256) ab[i] = f2b(row[i] * inv);
}

// ---------------------------------------------------------------------------
// k3: Xp_part[z][b][o][d] = sum_{l in half z} alpha[o][l] * X[l][d]  (bf16 MFMA)
// tile 64(o) x 128(d), BK=64, split-K=2.  1-D grid of 256, XCD-grouped by b.
// X tile is transposed 4x4 in registers into LDS [d][l] for the B operand.
// ---------------------------------------------------------------------------
__global__ __launch_bounds__(256) void k3(const float* __restrict__ X,
                                          const short* __restrict__ aBf,
                                          float* __restrict__ XpP) {
    __shared__ __align__(16) float ts[64][132];            // 33.8KB; aliased below
    short* Aal = (short*)&ts[0][0];                         // [64 o][64 l] swizzled
    short* Xs  = Aal + 64 * 64;                             // [128 d][64 l] swizzled
    const int tid = threadIdx.x;
    const int lane = tid & 63, wave = tid >> 6;
    const int wm = wave >> 1, wn = wave & 1;
    const int id = blockIdx.x;
    const int slot = id >> 3;
    const int b = (id & 7) * 2 + (slot >> 4);               // same-b -> same XCD (L2 reuse of alpha)
    const int inner = slot & 15;
    const int dt = inner & 7, z = inner >> 3;
    const int d0 = dt * 128;
    const float* Xb = X + (size_t)b * Ll * Dd;
    const short* ab = aBf + (size_t)b * OSo * Ll;
    float* outP = XpP + (size_t)z * ((size_t)Bb * OSo * Dd);
    f32x4 acc[2][4] = {};
    const int arow = tid >> 2, akofs = (tid & 3) * 16;
    for (int s = 0; s < 16; ++s) {
        const int l0 = z * 1024 + s * 64;
        #pragma unroll
        for (int w = 0; w < 2; ++w)                         // stage alpha rows
            *(s8v*)&Aal[swi(arow, akofs + w * 8)] = *(const s8v*)&ab[(size_t)arow * Ll + l0 + akofs + w * 8];
        #pragma unroll
        for (int p = 0; p < 2; ++p) {                       // stage X transposed (4x4 reg)
            const int q = tid + p * 256;
            const int lq = q >> 5, dq = q & 31;
            float4 v[4];
            #pragma unroll
            for (int i = 0; i < 4; ++i)
                v[i] = *(const float4*)&Xb[(size_t)(l0 + lq * 4 + i) * Dd + d0 + dq * 4];
            const float* f = (const float*)v;               // f[i*4+j]
            #pragma unroll
            for (int j = 0; j < 4; ++j) {
                const int rowd = dq * 4 + j;
                s4v sj;
                sj[0] = f2b(f[0 * 4 + j]);
                sj[1] = f2b(f[1 * 4 + j]);
                sj[2] = f2b(f[2 * 4 + j]);
                sj[3] = f2b(f[3 * 4 + j]);
                *(s4v*)&Xs[(rowd * 128 + ((lq * 8) ^ ((rowd & 7) << 4))) >> 1] = sj;
            }
        }
        __syncthreads();
        #pragma unroll
        for (int kk = 0; kk < 2; ++kk) {
            const int kb = kk * 32 + (lane >> 4) * 8;
            s8v a[2], bb[4];
            #pragma unroll
            for (int i = 0; i < 2; ++i)
                a[i] = *(const s8v*)&Aal[swi(wm * 32 + i * 16 + (lane & 15), kb)];
            #pragma unroll
            for (int j = 0; j < 4; ++j)
                bb[j] = *(const s8v*)&Xs[swi(wn * 64 + j * 16 + (lane & 15), kb)];
            #pragma unroll
            for (int i = 0; i < 2; ++i)
                #pragma unroll
                for (int j = 0; j < 4; ++j)
                    acc[i][j] = MF(a[i], bb[j], acc[i][j]);
        }
        __syncthreads();
    }
    #pragma unroll
    for (int i = 0; i < 2; ++i)
        #pragma unroll
        for (int j = 0; j < 4; ++j)
            #pragma unroll
            for (int r = 0; r < 4; ++r)
                ts[wm * 32 + i * 16 + (lane >> 4) * 4 + r][wn * 64 + j * 16 + (lane & 15)] = acc[i][j][r];
    __syncthreads();
    const int o = tid >> 2, dofs = (tid & 3) * 32;
    float* op = outP + ((size_t)b * OSo + o) * Dd + d0 + dofs;
    #pragma unroll
    for (int w = 0; w < 8; ++w)
        *(float4*)&op[w * 4] = *(float4*)&ts[o][dofs + w * 4];
}

// ---------------------------------------------------------------------------
// k3r: XpBf = bf16(part0 + part1)
// ---------------------------------------------------------------------------
__global__ __launch_bounds__(256) void k3r(const float* __restrict__ P, short* __restrict__ XpBf) {
    const size_t i = ((size_t)blockIdx.x * 256 + threadIdx.x) * 8;
    float4 a0 = *(const float4*)&P[i],           a1 = *(const float4*)&P[i + 4];
    float4 b0 = *(const float4*)&P[1048576 + i], b1 = *(const float4*)&P[1048576 + i + 4];
    s8v o;
    o[0] = f2b(a0.x + b0.x); o[1] = f2b(a0.y + b0.y); o[2] = f2b(a0.z + b0.z); o[3] = f2b(a0.w + b0.w);
    o[4] = f2b(a1.x + b1.x); o[5] = f2b(a1.y + b1.y); o[6] = f2b(a1.z + b1.z); o[7] = f2b(a1.w + b1.w);
    *(s8v*)&XpBf[i] = o;
}

// ---------------------------------------------------------------------------
// k4: Xh = bf16( relu( BN( Xp@h_w + h_b ) ) )   tile 64x64, K=1024, MFMA
// ---------------------------------------------------------------------------
__global__ __launch_bounds__(256) void k4(const short* __restrict__ XpBf,
                                          const short* __restrict__ h_wT,
                                          const float* __restrict__ h_b,
                                          const float* __restrict__ gamma,
                                          const float* __restrict__ beta,
                                          const float* __restrict__ mean,
                                          const float* __restrict__ var,
                                          short* __restrict__ Xh) {
    __shared__ __align__(16) short As[64 * 64];
    __shared__ __align__(16) short Bs[64 * 64];
    const int tid = threadIdx.x, lane = tid & 63, wave = tid >> 6;
    const int wm = wave >> 1, wn = wave & 1;
    const int h0 = blockIdx.x * 64, m0 = blockIdx.y * 64;
    const int r = tid >> 2, kofs = (tid & 3) * 16;
    f32x4 acc[2][2] = {};
    for (int k0 = 0; k0 < Dd; k0 += 64) {
        #pragma unroll
        for (int w = 0; w < 2; ++w) {
            *(s8v*)&As[swi(r, kofs + w * 8)] = *(const s8v*)&XpBf[(size_t)(m0 + r) * Dd + k0 + kofs + w * 8];
            *(s8v*)&Bs[swi(r, kofs + w * 8)] = *(const s8v*)&h_wT[(size_t)(h0 + r) * Dd + k0 + kofs + w * 8];
        }
        __syncthreads();
        #pragma unroll
        for (int kk = 0; kk < 2; ++kk) {
            const int kb = kk * 32 + (lane >> 4) * 8;
            s8v a[2], bb[2];
            #pragma unroll
            for (int i = 0; i < 2; ++i)
                a[i] = *(const s8v*)&As[swi(wm * 32 + i * 16 + (lane & 15), kb)];
            #pragma unroll
            for (int j = 0; j < 2; ++j)
                bb[j] = *(const s8v*)&Bs[swi(wn * 32 + j * 16 + (lane & 15), kb)];
            #pragma unroll
            for (int i = 0; i < 2; ++i)
                #pragma unroll
                for (int j = 0; j < 2; ++j)
                    acc[i][j] = MF(a[i], bb[j], acc[i][j]);
        }
        __syncthreads();
    }
    short* tsb = As;                                        // reuse As as [64][64] bf16
    #pragma unroll
    for (int j = 0; j < 2; ++j) {
        const int h = h0 + wn * 32 + j * 16 + (lane & 15);
        const float sc = gamma[h] * rsqrtf(var[h] + BN_EPS);
        const float of = (h_b[h] - mean[h]) * sc + beta[h];
        #pragma unroll
        for (int i = 0; i < 2; ++i)
            #pragma unroll
            for (int rr = 0; rr < 4; ++rr) {
                const int ml = wm * 32 + i * 16 + (lane >> 4) * 4 + rr;
                tsb[ml * 64 + wn * 32 + j * 16 + (lane & 15)] = f2b(fmaxf(0.f, acc[i][j][rr] * sc + of));
            }
    }
    __syncthreads();
    #pragma unroll
    for (int w = 0; w < 2; ++w)
        *(s8v*)&Xh[(size_t)(m0 + r) * LABh + h0 + kofs + w * 8] = *(const s8v*)&tsb[r * 64 + kofs + w * 8];
}

// ---------------------------------------------------------------------------
// k5: sc[b][c][o] = labDesc[cand]@Xh^T   tile 64(c)x64(o), K=1024, MFMA
// ---------------------------------------------------------------------------
__global__ __launch_bounds__(256) void k5(const int* __restrict__ cand,
                                          const float* __restrict__ labD,
                                          const short* __restrict__ Xh,
                                          float* __restrict__ sc) {
    __shared__ __align__(16) float ts[64][68];             // 17.4KB; aliased below
    short* As = (short*)&ts[0][0];
    short* Bs = As + 64 * 64;
    __shared__ int cidx[64];
    const int tid = threadIdx.x, lane = tid & 63, wave = tid >> 6;
    const int wm = wave >> 1, wn = wave & 1;
    const int b = blockIdx.y, c0 = blockIdx.x * 64;
    if (tid < 64) cidx[tid] = cand[b * NCc + c0 + tid];
    __syncthreads();
    const int r = tid >> 2, kofs = (tid & 3) * 16;
    const int ci = cidx[r];
    f32x4 acc[2][2] = {};
    for (int k0 = 0; k0 < LABh; k0 += 64) {
        const float* lp = labD + (size_t)ci * LABh + k0 + kofs;
        #pragma unroll
        for (int w = 0; w < 2; ++w) {
            float4 v0 = *(const float4*)&lp[w * 8];
            float4 v1 = *(const float4*)&lp[w * 8 + 4];
            s8v s;
            s[0]=f2b(v0.x); s[1]=f2b(v0.y); s[2]=f2b(v0.z); s[3]=f2b(v0.w);
            s[4]=f2b(v1.x); s[5]=f2b(v1.y); s[6]=f2b(v1.z); s[7]=f2b(v1.w);
            *(s8v*)&As[swi(r, kofs + w * 8)] = s;
            *(s8v*)&Bs[swi(r, kofs + w * 8)] = *(const s8v*)&Xh[(size_t)(b * OSo + r) * LABh + k0 + kofs + w * 8];
        }
        __syncthreads();
        #pragma unroll
        for (int kk = 0; kk < 2; ++kk) {
            const int kb = kk * 32 + (lane >> 4) * 8;
            s8v a[2], bb[2];
            #pragma unroll
            for (int i = 0; i < 2; ++i)
                a[i] = *(const s8v*)&As[swi(wm * 32 + i * 16 + (lane & 15), kb)];
            #pragma unroll
            for (int j = 0; j < 2; ++j)
                bb[j] = *(const s8v*)&Bs[swi(wn * 32 + j * 16 + (lane & 15), kb)];
            #pragma unroll
            for (int i = 0; i < 2; ++i)
                #pragma unroll
                for (int j = 0; j < 2; ++j)
                    acc[i][j] = MF(a[i], bb[j], acc[i][j]);
        }
        __syncthreads();
    }
    #pragma unroll
    for (int i = 0; i < 2; ++i)
        #pragma unroll
        for (int j = 0; j < 2; ++j)
            #pragma unroll
            for (int rr = 0; rr < 4; ++rr)
                ts[wm * 32 + i * 16 + (lane >> 4) * 4 + rr][wn * 32 + j * 16 + (lane & 15)] = acc[i][j][rr];
    __syncthreads();
    const int oofs = (tid & 3) * 16;
    float* sp = sc + ((size_t)b * NCc + c0 + r) * OSo + oofs;
    #pragma unroll
    for (int w = 0; w < 4; ++w)
        *(float4*)&sp[w * 4] = *(float4*)&ts[r][oofs + w * 4];
}

// ---------------------------------------------------------------------------
// k6: alpha2 = softmax over o; out[b][c][h] = sum_o alpha2 * Xh[o][h]
// 1-D grid of 256, XCD-grouped by b for Xh L2 reuse.
// ---------------------------------------------------------------------------
__global__ __launch_bounds__(256) void k6(const float* __restrict__ sc,
                                          const short* __restrict__ Xh,
                                          float* __restrict__ out) {
    __shared__ float al[16][64];
    const int tid = threadIdx.x;
    const int id = blockIdx.x;
    const int b = (id & 7) * 2 + ((id >> 3) >> 4);
    const int c0 = ((id >> 3) & 15) * 16;
    {
        const int cl = tid >> 4, t16 = tid & 15;
        const float* srow = sc + ((size_t)b * NCc + c0 + cl) * OSo;
        float v[4];
        float m = -1e30f;
        #pragma unroll
        for (int j = 0; j < 4; ++j) { v[j] = srow[t16 + j * 16]; m = fmaxf(m, v[j]); }
        #pragma unroll
        for (int off = 8; off; off >>= 1) m = fmaxf(m, __shfl_xor(m, off, 16));
        float s = 0.f;
        #pragma unroll
        for (int j = 0; j < 4; ++j) { v[j] = __expf(v[j] - m); s += v[j]; }
        #pragma unroll
        for (int off = 8; off; off >>= 1) s += __shfl_xor(s, off, 16);
        float inv = 1.f / s;
        #pragma unroll
        for (int j = 0; j < 4; ++j) al[cl][t16 + j * 16] = v[j] * inv;
    }
    __syncthreads();
    const short* xb = Xh + (size_t)b * OSo * LABh;
    float acc[16][4] = {};
    for (int o = 0; o < OSo; ++o) {
        s4v xv = *(const s4v*)&xb[(size_t)o * LABh + tid * 4];
        const float x0 = b2f(xv[0]), x1 = b2f(xv[1]), x2 = b2f(xv[2]), x3 = b2f(xv[3]);
        #pragma unroll
        for (int c = 0; c < 16; ++c) {
            const float w = al[c][o];
            acc[c][0] += w * x0; acc[c][1] += w * x1; acc[c][2] += w * x2; acc[c][3] += w * x3;
        }
    }
    #pragma unroll
    for (int c = 0; c < 16; ++c) {
        float4 v; v.x = acc[c][0]; v.y = acc[c][1]; v.z = acc[c][2]; v.w = acc[c][3];
        *(float4*)&out[((size_t)b * NCc + c0 + c) * LABh + tid * 4] = v;
    }
}

// ---------------------------------------------------------------------------
extern "C" void kernel_launch(void* const* d_in, const int* in_sizes, int n_in,
                              void* d_out, int out_size, void* d_ws, size_t ws_size,
                              hipStream_t stream) {
    (void)in_sizes; (void)n_in; (void)out_size; (void)ws_size;
    const float* X      = (const float*)d_in[0];
    const int*   cand   = (const int*)  d_in[1];
    const float* a_w    = (const float*)d_in[2];
    const float* a_b    = (const float*)d_in[3];
    const float* h_w    = (const float*)d_in[4];
    const float* h_b    = (const float*)d_in[5];
    const float* gamma  = (const float*)d_in[6];
    const float* beta   = (const float*)d_in[7];
    const float* mean   = (const float*)d_in[8];
    const float* var    = (const float*)d_in[9];
    const float* labDesc= (const float*)d_in[10];
    float* outp = (float*)d_out;

    char* ws = (char*)d_ws;
    float* St   = (float*)ws;                               // 8MB: St (k1/k2) then XpPart (k3)
    float* XpP  = St;
    short* aBf  = (short*)(ws + ((size_t)8  << 20));        // 4MB alpha bf16 (dead after k3)
    short* XpBf = (short*)(ws + ((size_t)8  << 20));        // 2MB (aliases aBf, k3r after k3)
    short* Xh   = (short*)(ws + ((size_t)10 << 20));        // 2MB
    float* scb  = (float*)(ws + ((size_t)12 << 20));        // 1MB
    short* a_wT = (short*)(ws + ((size_t)13 << 20));        // 128KB
    short* h_wT = (short*)(ws + ((size_t)14 << 20));        // 2MB

    k0 <<<272,          256, 0, stream>>>(h_w, a_w, h_wT, a_wT);
    k1 <<<dim3(16, 16), 256, 0, stream>>>(X, a_wT, a_b, St);
    k2 <<<Bb * OSo,     256, 0, stream>>>(St, aBf);
    k3 <<<256,          256, 0, stream>>>(X, aBf, XpP);
    k3r<<<512,          256, 0, stream>>>(XpP, XpBf);
    k4 <<<dim3(16, 16), 256, 0, stream>>>(XpBf, h_wT, h_b, gamma, beta, mean, var, Xh);
    k5 <<<dim3(4, 16),  256, 0, stream>>>(cand, labDesc, Xh, scb);
    k6 <<<256,          256, 0, stream>>>(scb, Xh, outp);
}

// Round 3
// 128.668 us; speedup vs baseline: 2.3355x; 1.1125x over previous
//
#include <hip/hip_runtime.h>
#include <math.h>

#define Bb   16
#define Ll   2048
#define Dd   1024
#define OSo  64
#define NCc  256
#define LABh 1024
#define BN_EPS 1e-5f

typedef short s8v  __attribute__((ext_vector_type(8)));   // 8 bf16 = 4 VGPR
typedef short s4v  __attribute__((ext_vector_type(4)));
typedef float f32x4 __attribute__((ext_vector_type(4)));

__device__ __forceinline__ short f2b(float f) {           // f32 -> bf16 RNE
    union { float f; unsigned u; } v; v.f = f;
    unsigned r = (v.u + 0x7fffu + ((v.u >> 16) & 1u)) >> 16;
    return (short)r;
}
__device__ __forceinline__ float b2f(short s) {
    union { unsigned u; float f; } v; v.u = ((unsigned)(unsigned short)s) << 16;
    return v.f;
}
// swizzled short-index into a [rows][64] bf16 LDS tile (row stride 128B).
// byte ^= ((row&7)<<4) spreads the 128B-stride rows across banks (G4).
__device__ __forceinline__ int swi(int row, int kElem) {
    return (row * 128 + ((kElem * 2) ^ ((row & 7) << 4))) >> 1;
}
__device__ __forceinline__ f32x4 MF(s8v a, s8v b, f32x4 c) {
    return __builtin_amdgcn_mfma_f32_16x16x32_bf16(a, b, c, 0, 0, 0);
}

// ---------------------------------------------------------------------------
// k0: transpose+convert weights.  id<256: h_w[1024][1024] -> h_wT bf16[1024][1024]
//     id>=256: a_w[1024][64] -> a_wT bf16[64][1024]
// ---------------------------------------------------------------------------
__global__ __launch_bounds__(256) void k0(const float* __restrict__ h_w,
                                          const float* __restrict__ a_w,
                                          short* __restrict__ h_wT,
                                          short* __restrict__ a_wT) {
    __shared__ float t[64][68];
    const int tid = threadIdx.x, id = blockIdx.x;
    const float* src; short* dst; int srw, d0, y0;
    if (id < 256) { src = h_w; dst = h_wT; srw = LABh; d0 = (id & 15) * 64; y0 = (id >> 4) * 64; }
    else          { src = a_w; dst = a_wT; srw = OSo;  d0 = (id - 256) * 64; y0 = 0; }
    const int r = tid >> 2, cofs = (tid & 3) * 16;
    #pragma unroll
    for (int w = 0; w < 4; ++w) {
        float4 v = *(const float4*)&src[(size_t)(d0 + r) * srw + y0 + cofs + w * 4];
        t[r][cofs + w * 4 + 0] = v.x;
        t[r][cofs + w * 4 + 1] = v.y;
        t[r][cofs + w * 4 + 2] = v.z;
        t[r][cofs + w * 4 + 3] = v.w;
    }
    __syncthreads();
    s8v o0, o1;
    #pragma unroll
    for (int e = 0; e < 8; ++e) { o0[e] = f2b(t[cofs + e][r]); o1[e] = f2b(t[cofs + 8 + e][r]); }
    *(s8v*)&dst[(size_t)(y0 + r) * Dd + d0 + cofs]     = o0;
    *(s8v*)&dst[(size_t)(y0 + r) * Dd + d0 + cofs + 8] = o1;
}

// ---------------------------------------------------------------------------
// k1: St[b][o][l] = X@a_w + a_b  via bf16 MFMA.  tile 64(l) x 64(o), K=1024
// grid (32 ltiles, 16 b) = 512 blocks (2/CU), 4 waves (2x2), wave tile 32x32
// ---------------------------------------------------------------------------
__global__ __launch_bounds__(256) void k1(const float* __restrict__ X,
                                          const short* __restrict__ a_wT,
                                          const float* __restrict__ a_b,
                                          float* __restrict__ St) {
    __shared__ __align__(16) float ts[64][65];             // 16.6KB; aliased below
    short* As = (short*)&ts[0][0];                          // [64 l][64 k] swizzled bf16
    short* Bs = As + 64 * 64;                               // [64 o][64 k] swizzled bf16
    const int tid = threadIdx.x;
    const int lane = tid & 63, wave = tid >> 6;
    const int wm = wave >> 1, wn = wave & 1;
    const int b = blockIdx.y, l0 = blockIdx.x * 64;
    const float* Xb = X + ((size_t)b * Ll + l0) * Dd;
    f32x4 acc[2][2] = {};
    const int r = tid >> 2, kofs = (tid & 3) * 16;
    for (int k0 = 0; k0 < Dd; k0 += 64) {
        #pragma unroll
        for (int w = 0; w < 2; ++w) {
            float4 v0 = *(const float4*)&Xb[(size_t)r * Dd + k0 + kofs + w * 8];
            float4 v1 = *(const float4*)&Xb[(size_t)r * Dd + k0 + kofs + w * 8 + 4];
            s8v s;
            s[0]=f2b(v0.x); s[1]=f2b(v0.y); s[2]=f2b(v0.z); s[3]=f2b(v0.w);
            s[4]=f2b(v1.x); s[5]=f2b(v1.y); s[6]=f2b(v1.z); s[7]=f2b(v1.w);
            *(s8v*)&As[swi(r, kofs + w * 8)] = s;
            *(s8v*)&Bs[swi(r, kofs + w * 8)] = *(const s8v*)&a_wT[(size_t)r * Dd + k0 + kofs + w * 8];
        }
        __syncthreads();
        #pragma unroll
        for (int kk = 0; kk < 2; ++kk) {
            const int kb = kk * 32 + (lane >> 4) * 8;
            s8v a[2], bb[2];
            #pragma unroll
            for (int i = 0; i < 2; ++i)
                a[i] = *(const s8v*)&As[swi(wm * 32 + i * 16 + (lane & 15), kb)];
            #pragma unroll
            for (int j = 0; j < 2; ++j)
                bb[j] = *(const s8v*)&Bs[swi(wn * 32 + j * 16 + (lane & 15), kb)];
            #pragma unroll
            for (int i = 0; i < 2; ++i)
                #pragma unroll
                for (int j = 0; j < 2; ++j)
                    acc[i][j] = MF(a[i], bb[j], acc[i][j]);
        }
        __syncthreads();
    }
    // epilogue: ts[l][o] then write St[o][l] rows
    #pragma unroll
    for (int i = 0; i < 2; ++i)
        #pragma unroll
        for (int j = 0; j < 2; ++j)
            #pragma unroll
            for (int rr = 0; rr < 4; ++rr)
                ts[wm * 32 + i * 16 + (lane >> 4) * 4 + rr][wn * 32 + j * 16 + (lane & 15)] = acc[i][j][rr];
    __syncthreads();
    const int o = tid >> 2, lofs = (tid & 3) * 16;
    const float bias = a_b[o];
    float* Sp = St + ((size_t)b * OSo + o) * Ll + l0 + lofs;
    #pragma unroll
    for (int w = 0; w < 4; ++w) {
        float4 v;
        v.x = ts[lofs + w * 4 + 0][o] + bias;
        v.y = ts[lofs + w * 4 + 1][o] + bias;
        v.z = ts[lofs + w * 4 + 2][o] + bias;
        v.w = ts[lofs + w * 4 + 3][o] + bias;
        *(float4*)&Sp[w * 4] = v;
    }
}

// ---------------------------------------------------------------------------
// k2: softmax over L per (b,o) row; St f32 in -> alpha bf16 out
// ---------------------------------------------------------------------------
__global__ __launch_bounds__(256) void k2(const float* __restrict__ St, short* __restrict__ aBf) {
    __shared__ float row[Ll];
    __shared__ float red[8];
    const float* p = St + (size_t)blockIdx.x * Ll;
    short* ab = aBf + (size_t)blockIdx.x * Ll;
    const int tid = threadIdx.x;
    const int wave = tid >> 6, lane = tid & 63;
    float m = -1e30f;
    for (int i = tid; i < Ll; i += 256) { float v = p[i]; row[i] = v; m = fmaxf(m, v); }
    #pragma unroll
    for (int off = 32; off; off >>= 1) m = fmaxf(m, __shfl_down(m, off));
    if (lane == 0) red[wave] = m;
    __syncthreads();
    if (tid == 0) red[4] = fmaxf(fmaxf(red[0], red[1]), fmaxf(red[2], red[3]));
    __syncthreads();
    const float M = red[4];
    float s = 0.f;
    for (int i = tid; i < Ll; i += 256) { float e = __expf(row[i] - M); row[i] = e; s += e; }
    __syncthreads();
    #pragma unroll
    for (int off = 32; off; off >>= 1) s += __shfl_down(s, off);
    if (lane == 0) red[wave] = s;
    __syncthreads();
    if (tid == 0) red[4] = 1.f / (red[0] + red[1] + red[2] + red[3]);
    __syncthreads();
    const float inv = red[4];
    for (int i = tid; i < Ll; i += 256) ab[i] = f2b(row[i] * inv);
}

// ---------------------------------------------------------------------------
// k3: Xp_part[z][b][o][d] = sum_{l in half z} alpha[o][l] * X[l][d]  (bf16 MFMA)
// tile 64(o) x 64(d), BK=64, split-K=2.  512 blocks (2/CU), XCD-grouped by b.
// X staged transposed via 4x4 reg transpose; thread map (lq=tid&15, dq=tid>>4)
// makes the transposed LDS stores bank-uniform (was 16-way conflicted).
// ---------------------------------------------------------------------------
__global__ __launch_bounds__(256) void k3(const float* __restrict__ X,
                                          const short* __restrict__ aBf,
                                          float* __restrict__ XpP) {
    __shared__ __align__(16) float ts[64][68];             // 17.4KB; aliased below
    short* Aal = (short*)&ts[0][0];                         // [64 o][64 l] swizzled
    short* Xs  = Aal + 64 * 64;                             // [64 d][64 l] swizzled
    const int tid = threadIdx.x;
    const int lane = tid & 63, wave = tid >> 6;
    const int wm = wave >> 1, wn = wave & 1;
    const int id = blockIdx.x;
    const int slot = id >> 3;
    const int b = (id & 7) * 2 + (slot >> 5);               // same-b -> same XCD (L2 reuse of alpha)
    const int inner = slot & 31;
    const int dt = inner & 15, z = inner >> 4;
    const int d0 = dt * 64;
    const float* Xb = X + (size_t)b * Ll * Dd;
    const short* ab = aBf + (size_t)b * OSo * Ll;
    float* outP = XpP + (size_t)z * ((size_t)Bb * OSo * Dd);
    f32x4 acc[2][2] = {};
    const int arow = tid >> 2, akofs = (tid & 3) * 16;      // alpha staging map
    const int lq = tid & 15, dq = tid >> 4;                 // X staging map
    for (int s = 0; s < 16; ++s) {
        const int l0 = z * 1024 + s * 64;
        #pragma unroll
        for (int w = 0; w < 2; ++w)                         // stage alpha rows [o][l]
            *(s8v*)&Aal[swi(arow, akofs + w * 8)] = *(const s8v*)&ab[(size_t)arow * Ll + l0 + akofs + w * 8];
        {                                                   // stage X transposed [d][l]
            float4 v[4];
            #pragma unroll
            for (int i = 0; i < 4; ++i)
                v[i] = *(const float4*)&Xb[(size_t)(l0 + lq * 4 + i) * Dd + d0 + dq * 4];
            const float* f = (const float*)v;               // f[i*4+j] = X[l=lq*4+i][d=dq*4+j]
            #pragma unroll
            for (int j = 0; j < 4; ++j) {
                const int rowd = dq * 4 + j;
                s4v sj;
                sj[0] = f2b(f[0 * 4 + j]);
                sj[1] = f2b(f[1 * 4 + j]);
                sj[2] = f2b(f[2 * 4 + j]);
                sj[3] = f2b(f[3 * 4 + j]);
                *(s4v*)&Xs[swi(rowd, lq * 4)] = sj;
            }
        }
        __syncthreads();
        #pragma unroll
        for (int kk = 0; kk < 2; ++kk) {
            const int kb = kk * 32 + (lane >> 4) * 8;
            s8v a[2], bb[2];
            #pragma unroll
            for (int i = 0; i < 2; ++i)
                a[i] = *(const s8v*)&Aal[swi(wm * 32 + i * 16 + (lane & 15), kb)];
            #pragma unroll
            for (int j = 0; j < 2; ++j)
                bb[j] = *(const s8v*)&Xs[swi(wn * 32 + j * 16 + (lane & 15), kb)];
            #pragma unroll
            for (int i = 0; i < 2; ++i)
                #pragma unroll
                for (int j = 0; j < 2; ++j)
                    acc[i][j] = MF(a[i], bb[j], acc[i][j]);
        }
        __syncthreads();
    }
    #pragma unroll
    for (int i = 0; i < 2; ++i)
        #pragma unroll
        for (int j = 0; j < 2; ++j)
            #pragma unroll
            for (int rr = 0; rr < 4; ++rr)
                ts[wm * 32 + i * 16 + (lane >> 4) * 4 + rr][wn * 32 + j * 16 + (lane & 15)] = acc[i][j][rr];
    __syncthreads();
    const int o = tid >> 2, dofs = (tid & 3) * 16;
    float* op = outP + ((size_t)b * OSo + o) * Dd + d0 + dofs;
    #pragma unroll
    for (int w = 0; w < 4; ++w)
        *(float4*)&op[w * 4] = *(float4*)&ts[o][dofs + w * 4];
}

// ---------------------------------------------------------------------------
// k4: Xh = bf16( relu( BN( (XpP0+XpP1)@h_w + h_b ) ) )  tile 64x64, K=1024, MFMA
// split-K reduce of k3 fused into the A-operand staging (kills k3r).
// ---------------------------------------------------------------------------
__global__ __launch_bounds__(256) void k4(const float* __restrict__ XpP,
                                          const short* __restrict__ h_wT,
                                          const float* __restrict__ h_b,
                                          const float* __restrict__ gamma,
                                          const float* __restrict__ beta,
                                          const float* __restrict__ mean,
                                          const float* __restrict__ var,
                                          short* __restrict__ Xh) {
    __shared__ __align__(16) short As[64 * 64];
    __shared__ __align__(16) short Bs[64 * 64];
    const int tid = threadIdx.x, lane = tid & 63, wave = tid >> 6;
    const int wm = wave >> 1, wn = wave & 1;
    const int h0 = blockIdx.x * 64, m0 = blockIdx.y * 64;
    const int r = tid >> 2, kofs = (tid & 3) * 16;
    f32x4 acc[2][2] = {};
    for (int k0 = 0; k0 < Dd; k0 += 64) {
        #pragma unroll
        for (int w = 0; w < 2; ++w) {
            const float* p0 = XpP + (size_t)(m0 + r) * Dd + k0 + kofs + w * 8;
            const float* p1 = p0 + (size_t)Bb * OSo * Dd;
            float4 a0 = *(const float4*)&p0[0], a1 = *(const float4*)&p0[4];
            float4 b0 = *(const float4*)&p1[0], b1 = *(const float4*)&p1[4];
            s8v s;
            s[0]=f2b(a0.x+b0.x); s[1]=f2b(a0.y+b0.y); s[2]=f2b(a0.z+b0.z); s[3]=f2b(a0.w+b0.w);
            s[4]=f2b(a1.x+b1.x); s[5]=f2b(a1.y+b1.y); s[6]=f2b(a1.z+b1.z); s[7]=f2b(a1.w+b1.w);
            *(s8v*)&As[swi(r, kofs + w * 8)] = s;
            *(s8v*)&Bs[swi(r, kofs + w * 8)] = *(const s8v*)&h_wT[(size_t)(h0 + r) * Dd + k0 + kofs + w * 8];
        }
        __syncthreads();
        #pragma unroll
        for (int kk = 0; kk < 2; ++kk) {
            const int kb = kk * 32 + (lane >> 4) * 8;
            s8v a[2], bb[2];
            #pragma unroll
            for (int i = 0; i < 2; ++i)
                a[i] = *(const s8v*)&As[swi(wm * 32 + i * 16 + (lane & 15), kb)];
            #pragma unroll
            for (int j = 0; j < 2; ++j)
                bb[j] = *(const s8v*)&Bs[swi(wn * 32 + j * 16 + (lane & 15), kb)];
            #pragma unroll
            for (int i = 0; i < 2; ++i)
                #pragma unroll
                for (int j = 0; j < 2; ++j)
                    acc[i][j] = MF(a[i], bb[j], acc[i][j]);
        }
        __syncthreads();
    }
    short* tsb = As;                                        // reuse As as [64][64] bf16
    #pragma unroll
    for (int j = 0; j < 2; ++j) {
        const int h = h0 + wn * 32 + j * 16 + (lane & 15);
        const float sc = gamma[h] * rsqrtf(var[h] + BN_EPS);
        const float of = (h_b[h] - mean[h]) * sc + beta[h];
        #pragma unroll
        for (int i = 0; i < 2; ++i)
            #pragma unroll
            for (int rr = 0; rr < 4; ++rr) {
                const int ml = wm * 32 + i * 16 + (lane >> 4) * 4 + rr;
                tsb[ml * 64 + wn * 32 + j * 16 + (lane & 15)] = f2b(fmaxf(0.f, acc[i][j][rr] * sc + of));
            }
    }
    __syncthreads();
    #pragma unroll
    for (int w = 0; w < 2; ++w)
        *(s8v*)&Xh[(size_t)(m0 + r) * LABh + h0 + kofs + w * 8] = *(const s8v*)&tsb[r * 64 + kofs + w * 8];
}

// ---------------------------------------------------------------------------
// k5: sc[b][c][o] = labDesc[cand]@Xh^T   tile 64(c)x64(o), K=1024, MFMA
// ---------------------------------------------------------------------------
__global__ __launch_bounds__(256) void k5(const int* __restrict__ cand,
                                          const float* __restrict__ labD,
                                          const short* __restrict__ Xh,
                                          float* __restrict__ sc) {
    __shared__ __align__(16) float ts[64][68];             // 17.4KB; aliased below
    short* As = (short*)&ts[0][0];
    short* Bs = As + 64 * 64;
    __shared__ int cidx[64];
    const int tid = threadIdx.x, lane = tid & 63, wave = tid >> 6;
    const int wm = wave >> 1, wn = wave & 1;
    const int b = blockIdx.y, c0 = blockIdx.x * 64;
    if (tid < 64) cidx[tid] = cand[b * NCc + c0 + tid];
    __syncthreads();
    const int r = tid >> 2, kofs = (tid & 3) * 16;
    const int ci = cidx[r];
    f32x4 acc[2][2] = {};
    for (int k0 = 0; k0 < LABh; k0 += 64) {
        const float* lp = labD + (size_t)ci * LABh + k0 + kofs;
        #pragma unroll
        for (int w = 0; w < 2; ++w) {
            float4 v0 = *(const float4*)&lp[w * 8];
            float4 v1 = *(const float4*)&lp[w * 8 + 4];
            s8v s;
            s[0]=f2b(v0.x); s[1]=f2b(v0.y); s[2]=f2b(v0.z); s[3]=f2b(v0.w);
            s[4]=f2b(v1.x); s[5]=f2b(v1.y); s[6]=f2b(v1.z); s[7]=f2b(v1.w);
            *(s8v*)&As[swi(r, kofs + w * 8)] = s;
            *(s8v*)&Bs[swi(r, kofs + w * 8)] = *(const s8v*)&Xh[(size_t)(b * OSo + r) * LABh + k0 + kofs + w * 8];
        }
        __syncthreads();
        #pragma unroll
        for (int kk = 0; kk < 2; ++kk) {
            const int kb = kk * 32 + (lane >> 4) * 8;
            s8v a[2], bb[2];
            #pragma unroll
            for (int i = 0; i < 2; ++i)
                a[i] = *(const s8v*)&As[swi(wm * 32 + i * 16 + (lane & 15), kb)];
            #pragma unroll
            for (int j = 0; j < 2; ++j)
                bb[j] = *(const s8v*)&Bs[swi(wn * 32 + j * 16 + (lane & 15), kb)];
            #pragma unroll
            for (int i = 0; i < 2; ++i)
                #pragma unroll
                for (int j = 0; j < 2; ++j)
                    acc[i][j] = MF(a[i], bb[j], acc[i][j]);
        }
        __syncthreads();
    }
    #pragma unroll
    for (int i = 0; i < 2; ++i)
        #pragma unroll
        for (int j = 0; j < 2; ++j)
            #pragma unroll
            for (int rr = 0; rr < 4; ++rr)
                ts[wm * 32 + i * 16 + (lane >> 4) * 4 + rr][wn * 32 + j * 16 + (lane & 15)] = acc[i][j][rr];
    __syncthreads();
    const int oofs = (tid & 3) * 16;
    float* sp = sc + ((size_t)b * NCc + c0 + r) * OSo + oofs;
    #pragma unroll
    for (int w = 0; w < 4; ++w)
        *(float4*)&sp[w * 4] = *(float4*)&ts[r][oofs + w * 4];
}

// ---------------------------------------------------------------------------
// k6: alpha2 = softmax over o; out[b][c][h] = sum_o alpha2 * Xh[o][h]
// 1-D grid of 256, XCD-grouped by b for Xh L2 reuse.
// ---------------------------------------------------------------------------
__global__ __launch_bounds__(256) void k6(const float* __restrict__ sc,
                                          const short* __restrict__ Xh,
                                          float* __restrict__ out) {
    __shared__ float al[16][64];
    const int tid = threadIdx.x;
    const int id = blockIdx.x;
    const int b = (id & 7) * 2 + ((id >> 3) >> 4);
    const int c0 = ((id >> 3) & 15) * 16;
    {
        const int cl = tid >> 4, t16 = tid & 15;
        const float* srow = sc + ((size_t)b * NCc + c0 + cl) * OSo;
        float v[4];
        float m = -1e30f;
        #pragma unroll
        for (int j = 0; j < 4; ++j) { v[j] = srow[t16 + j * 16]; m = fmaxf(m, v[j]); }
        #pragma unroll
        for (int off = 8; off; off >>= 1) m = fmaxf(m, __shfl_xor(m, off, 16));
        float s = 0.f;
        #pragma unroll
        for (int j = 0; j < 4; ++j) { v[j] = __expf(v[j] - m); s += v[j]; }
        #pragma unroll
        for (int off = 8; off; off >>= 1) s += __shfl_xor(s, off, 16);
        float inv = 1.f / s;
        #pragma unroll
        for (int j = 0; j < 4; ++j) al[cl][t16 + j * 16] = v[j] * inv;
    }
    __syncthreads();
    const short* xb = Xh + (size_t)b * OSo * LABh;
    float acc[16][4] = {};
    for (int o = 0; o < OSo; ++o) {
        s4v xv = *(const s4v*)&xb[(size_t)o * LABh + tid * 4];
        const float x0 = b2f(xv[0]), x1 = b2f(xv[1]), x2 = b2f(xv[2]), x3 = b2f(xv[3]);
        #pragma unroll
        for (int c = 0; c < 16; ++c) {
            const float w = al[c][o];
            acc[c][0] += w * x0; acc[c][1] += w * x1; acc[c][2] += w * x2; acc[c][3] += w * x3;
        }
    }
    #pragma unroll
    for (int c = 0; c < 16; ++c) {
        float4 v; v.x = acc[c][0]; v.y = acc[c][1]; v.z = acc[c][2]; v.w = acc[c][3];
        *(float4*)&out[((size_t)b * NCc + c0 + c) * LABh + tid * 4] = v;
    }
}

// ---------------------------------------------------------------------------
extern "C" void kernel_launch(void* const* d_in, const int* in_sizes, int n_in,
                              void* d_out, int out_size, void* d_ws, size_t ws_size,
                              hipStream_t stream) {
    (void)in_sizes; (void)n_in; (void)out_size; (void)ws_size;
    const float* X      = (const float*)d_in[0];
    const int*   cand   = (const int*)  d_in[1];
    const float* a_w    = (const float*)d_in[2];
    const float* a_b    = (const float*)d_in[3];
    const float* h_w    = (const float*)d_in[4];
    const float* h_b    = (const float*)d_in[5];
    const float* gamma  = (const float*)d_in[6];
    const float* beta   = (const float*)d_in[7];
    const float* mean   = (const float*)d_in[8];
    const float* var    = (const float*)d_in[9];
    const float* labDesc= (const float*)d_in[10];
    float* outp = (float*)d_out;

    char* ws = (char*)d_ws;
    float* St   = (float*)ws;                               // 8MB: St (k1/k2) then XpP (k3, 2x4MB)
    float* XpP  = St;
    short* aBf  = (short*)(ws + ((size_t)8  << 20));        // 4MB alpha bf16
    short* Xh   = (short*)(ws + ((size_t)12 << 20));        // 2MB
    float* scb  = (float*)(ws + ((size_t)14 << 20));        // 1MB
    short* a_wT = (short*)(ws + ((size_t)15 << 20));        // 128KB
    short* h_wT = (short*)(ws + ((size_t)16 << 20));        // 2MB

    k0 <<<272,          256, 0, stream>>>(h_w, a_w, h_wT, a_wT);
    k1 <<<dim3(32, 16), 256, 0, stream>>>(X, a_wT, a_b, St);
    k2 <<<Bb * OSo,     256, 0, stream>>>(St, aBf);
    k3 <<<512,          256, 0, stream>>>(X, aBf, XpP);
    k4 <<<dim3(16, 16), 256, 0, stream>>>(XpP, h_wT, h_b, gamma, beta, mean, var, Xh);
    k5 <<<dim3(4, 16),  256, 0, stream>>>(cand, labDesc, Xh, scb);
    k6 <<<256,          256, 0, stream>>>(scb, Xh, outp);
}

// Round 4
// 112.003 us; speedup vs baseline: 2.6830x; 1.1488x over previous
//
#include <hip/hip_runtime.h>
#include <math.h>

#define Bb   16
#define Ll   2048
#define Dd   1024
#define OSo  64
#define NCc  256
#define LABh 1024
#define BN_EPS 1e-5f

typedef short s8v  __attribute__((ext_vector_type(8)));   // 8 bf16 = 4 VGPR
typedef short s4v  __attribute__((ext_vector_type(4)));
typedef float f32x4 __attribute__((ext_vector_type(4)));

__device__ __forceinline__ short f2b(float f) {           // f32 -> bf16 RNE
    union { float f; unsigned u; } v; v.f = f;
    unsigned r = (v.u + 0x7fffu + ((v.u >> 16) & 1u)) >> 16;
    return (short)r;
}
__device__ __forceinline__ float b2f(short s) {
    union { unsigned u; float f; } v; v.u = ((unsigned)(unsigned short)s) << 16;
    return v.f;
}
// swizzled short-index into a [rows][64] bf16 LDS tile (row stride 128B).
__device__ __forceinline__ int swi(int row, int kElem) {
    return (row * 128 + ((kElem * 2) ^ ((row & 7) << 4))) >> 1;
}
__device__ __forceinline__ f32x4 MF(s8v a, s8v b, f32x4 c) {
    return __builtin_amdgcn_mfma_f32_16x16x32_bf16(a, b, c, 0, 0, 0);
}

// ---------------------------------------------------------------------------
// k0: transpose+convert weights.
// ---------------------------------------------------------------------------
__global__ __launch_bounds__(256) void k0(const float* __restrict__ h_w,
                                          const float* __restrict__ a_w,
                                          short* __restrict__ h_wT,
                                          short* __restrict__ a_wT) {
    __shared__ float t[64][68];
    const int tid = threadIdx.x, id = blockIdx.x;
    const float* src; short* dst; int srw, d0, y0;
    if (id < 256) { src = h_w; dst = h_wT; srw = LABh; d0 = (id & 15) * 64; y0 = (id >> 4) * 64; }
    else          { src = a_w; dst = a_wT; srw = OSo;  d0 = (id - 256) * 64; y0 = 0; }
    const int r = tid >> 2, cofs = (tid & 3) * 16;
    #pragma unroll
    for (int w = 0; w < 4; ++w) {
        float4 v = *(const float4*)&src[(size_t)(d0 + r) * srw + y0 + cofs + w * 4];
        t[r][cofs + w * 4 + 0] = v.x;
        t[r][cofs + w * 4 + 1] = v.y;
        t[r][cofs + w * 4 + 2] = v.z;
        t[r][cofs + w * 4 + 3] = v.w;
    }
    __syncthreads();
    s8v o0, o1;
    #pragma unroll
    for (int e = 0; e < 8; ++e) { o0[e] = f2b(t[cofs + e][r]); o1[e] = f2b(t[cofs + 8 + e][r]); }
    *(s8v*)&dst[(size_t)(y0 + r) * Dd + d0 + cofs]     = o0;
    *(s8v*)&dst[(size_t)(y0 + r) * Dd + d0 + cofs + 8] = o1;
}

// ---------------------------------------------------------------------------
// k1: St[b][o][l] = X@a_w + a_b.  tile 64(l)x64(o), K=1024, dbuf+prefetch.
// ---------------------------------------------------------------------------
struct R1 { float4 x[4]; s8v w[2]; };

__global__ __launch_bounds__(256) void k1(const float* __restrict__ X,
                                          const short* __restrict__ a_wT,
                                          const float* __restrict__ a_b,
                                          float* __restrict__ St) {
    __shared__ __align__(16) char smem[32768];
    float (*ts)[65] = (float(*)[65])smem;                   // epilogue alias
    const int tid = threadIdx.x;
    const int lane = tid & 63, wave = tid >> 6;
    const int wm = wave >> 1, wn = wave & 1;
    const int b = blockIdx.y, l0 = blockIdx.x * 64;
    const float* Xb = X + ((size_t)b * Ll + l0) * Dd;
    const int r = tid >> 2, kofs = (tid & 3) * 16;
    f32x4 acc[2][2] = {};
    R1 cur, nxt;
    #pragma unroll
    for (int w = 0; w < 2; ++w) {
        cur.x[2*w]   = *(const float4*)&Xb[(size_t)r * Dd + kofs + w * 8];
        cur.x[2*w+1] = *(const float4*)&Xb[(size_t)r * Dd + kofs + w * 8 + 4];
        cur.w[w]     = *(const s8v*)&a_wT[(size_t)r * Dd + kofs + w * 8];
    }
    #pragma unroll
    for (int t = 0; t < 16; ++t) {
        short* As = (short*)(smem + (t & 1) * 8192);
        short* Bs = (short*)(smem + 16384 + (t & 1) * 8192);
        #pragma unroll
        for (int w = 0; w < 2; ++w) {
            const float* f0 = (const float*)&cur.x[2*w];
            s8v s;
            s[0]=f2b(f0[0]); s[1]=f2b(f0[1]); s[2]=f2b(f0[2]); s[3]=f2b(f0[3]);
            s[4]=f2b(f0[4]); s[5]=f2b(f0[5]); s[6]=f2b(f0[6]); s[7]=f2b(f0[7]);
            *(s8v*)&As[swi(r, kofs + w * 8)] = s;
            *(s8v*)&Bs[swi(r, kofs + w * 8)] = cur.w[w];
        }
        __syncthreads();
        if (t < 15) {
            const int k0 = (t + 1) * 64;
            #pragma unroll
            for (int w = 0; w < 2; ++w) {
                nxt.x[2*w]   = *(const float4*)&Xb[(size_t)r * Dd + k0 + kofs + w * 8];
                nxt.x[2*w+1] = *(const float4*)&Xb[(size_t)r * Dd + k0 + kofs + w * 8 + 4];
                nxt.w[w]     = *(const s8v*)&a_wT[(size_t)r * Dd + k0 + kofs + w * 8];
            }
        }
        #pragma unroll
        for (int kk = 0; kk < 2; ++kk) {
            const int kb = kk * 32 + (lane >> 4) * 8;
            s8v a[2], bb[2];
            #pragma unroll
            for (int i = 0; i < 2; ++i)
                a[i] = *(const s8v*)&As[swi(wm * 32 + i * 16 + (lane & 15), kb)];
            #pragma unroll
            for (int j = 0; j < 2; ++j)
                bb[j] = *(const s8v*)&Bs[swi(wn * 32 + j * 16 + (lane & 15), kb)];
            #pragma unroll
            for (int i = 0; i < 2; ++i)
                #pragma unroll
                for (int j = 0; j < 2; ++j)
                    acc[i][j] = MF(a[i], bb[j], acc[i][j]);
        }
        if (t < 15) cur = nxt;
    }
    __syncthreads();                                        // before ts alias writes
    #pragma unroll
    for (int i = 0; i < 2; ++i)
        #pragma unroll
        for (int j = 0; j < 2; ++j)
            #pragma unroll
            for (int rr = 0; rr < 4; ++rr)
                ts[wm * 32 + i * 16 + (lane >> 4) * 4 + rr][wn * 32 + j * 16 + (lane & 15)] = acc[i][j][rr];
    __syncthreads();
    const int o = tid >> 2, lofs = (tid & 3) * 16;
    const float bias = a_b[o];
    float* Sp = St + ((size_t)b * OSo + o) * Ll + l0 + lofs;
    #pragma unroll
    for (int w = 0; w < 4; ++w) {
        float4 v;
        v.x = ts[lofs + w * 4 + 0][o] + bias;
        v.y = ts[lofs + w * 4 + 1][o] + bias;
        v.z = ts[lofs + w * 4 + 2][o] + bias;
        v.w = ts[lofs + w * 4 + 3][o] + bias;
        *(float4*)&Sp[w * 4] = v;
    }
}

// ---------------------------------------------------------------------------
// k2: softmax over L per (b,o) row; St f32 in -> alpha bf16 out
// ---------------------------------------------------------------------------
__global__ __launch_bounds__(256) void k2(const float* __restrict__ St, short* __restrict__ aBf) {
    __shared__ float row[Ll];
    __shared__ float red[8];
    const float* p = St + (size_t)blockIdx.x * Ll;
    short* ab = aBf + (size_t)blockIdx.x * Ll;
    const int tid = threadIdx.x;
    const int wave = tid >> 6, lane = tid & 63;
    float m = -1e30f;
    for (int i = tid; i < Ll; i += 256) { float v = p[i]; row[i] = v; m = fmaxf(m, v); }
    #pragma unroll
    for (int off = 32; off; off >>= 1) m = fmaxf(m, __shfl_down(m, off));
    if (lane == 0) red[wave] = m;
    __syncthreads();
    if (tid == 0) red[4] = fmaxf(fmaxf(red[0], red[1]), fmaxf(red[2], red[3]));
    __syncthreads();
    const float M = red[4];
    float s = 0.f;
    for (int i = tid; i < Ll; i += 256) { float e = __expf(row[i] - M); row[i] = e; s += e; }
    __syncthreads();
    #pragma unroll
    for (int off = 32; off; off >>= 1) s += __shfl_down(s, off);
    if (lane == 0) red[wave] = s;
    __syncthreads();
    if (tid == 0) red[4] = 1.f / (red[0] + red[1] + red[2] + red[3]);
    __syncthreads();
    const float inv = red[4];
    for (int i = tid; i < Ll; i += 256) ab[i] = f2b(row[i] * inv);
}

// ---------------------------------------------------------------------------
// k3: Xp_part[z] = alpha_half @ X_half.  tile 64(o)x64(d), split-K=2,
// dbuf+prefetch; X transposed 4x4 in regs with bank-uniform store map.
// ---------------------------------------------------------------------------
struct R3 { s8v al[2]; float4 xv[4]; };

__global__ __launch_bounds__(256) void k3(const float* __restrict__ X,
                                          const short* __restrict__ aBf,
                                          float* __restrict__ XpP) {
    __shared__ __align__(16) char smem[32768];
    float (*ts)[68] = (float(*)[68])smem;                   // 17.4KB epilogue alias
    const int tid = threadIdx.x;
    const int lane = tid & 63, wave = tid >> 6;
    const int wm = wave >> 1, wn = wave & 1;
    const int id = blockIdx.x;
    const int slot = id >> 3;
    const int b = (id & 7) * 2 + (slot >> 5);
    const int inner = slot & 31;
    const int dt = inner & 15, z = inner >> 4;
    const int d0 = dt * 64;
    const float* Xb = X + (size_t)b * Ll * Dd;
    const short* ab = aBf + (size_t)b * OSo * Ll;
    float* outP = XpP + (size_t)z * ((size_t)Bb * OSo * Dd);
    f32x4 acc[2][2] = {};
    const int arow = tid >> 2, akofs = (tid & 3) * 16;
    const int lq = tid & 15, dq = tid >> 4;
    const int lbase = z * 1024;
    R3 cur, nxt;
    #pragma unroll
    for (int w = 0; w < 2; ++w)
        cur.al[w] = *(const s8v*)&ab[(size_t)arow * Ll + lbase + akofs + w * 8];
    #pragma unroll
    for (int i = 0; i < 4; ++i)
        cur.xv[i] = *(const float4*)&Xb[(size_t)(lbase + lq * 4 + i) * Dd + d0 + dq * 4];
    #pragma unroll
    for (int t = 0; t < 16; ++t) {
        short* Aal = (short*)(smem + (t & 1) * 8192);
        short* Xs  = (short*)(smem + 16384 + (t & 1) * 8192);
        #pragma unroll
        for (int w = 0; w < 2; ++w)
            *(s8v*)&Aal[swi(arow, akofs + w * 8)] = cur.al[w];
        {
            const float* f = (const float*)cur.xv;          // f[i*4+j] = X[l=lq*4+i][d=dq*4+j]
            #pragma unroll
            for (int j = 0; j < 4; ++j) {
                const int rowd = dq * 4 + j;
                s4v sj;
                sj[0] = f2b(f[0 * 4 + j]);
                sj[1] = f2b(f[1 * 4 + j]);
                sj[2] = f2b(f[2 * 4 + j]);
                sj[3] = f2b(f[3 * 4 + j]);
                *(s4v*)&Xs[swi(rowd, lq * 4)] = sj;
            }
        }
        __syncthreads();
        if (t < 15) {
            const int l0 = lbase + (t + 1) * 64;
            #pragma unroll
            for (int w = 0; w < 2; ++w)
                nxt.al[w] = *(const s8v*)&ab[(size_t)arow * Ll + l0 + akofs + w * 8];
            #pragma unroll
            for (int i = 0; i < 4; ++i)
                nxt.xv[i] = *(const float4*)&Xb[(size_t)(l0 + lq * 4 + i) * Dd + d0 + dq * 4];
        }
        #pragma unroll
        for (int kk = 0; kk < 2; ++kk) {
            const int kb = kk * 32 + (lane >> 4) * 8;
            s8v a[2], bb[2];
            #pragma unroll
            for (int i = 0; i < 2; ++i)
                a[i] = *(const s8v*)&Aal[swi(wm * 32 + i * 16 + (lane & 15), kb)];
            #pragma unroll
            for (int j = 0; j < 2; ++j)
                bb[j] = *(const s8v*)&Xs[swi(wn * 32 + j * 16 + (lane & 15), kb)];
            #pragma unroll
            for (int i = 0; i < 2; ++i)
                #pragma unroll
                for (int j = 0; j < 2; ++j)
                    acc[i][j] = MF(a[i], bb[j], acc[i][j]);
        }
        if (t < 15) cur = nxt;
    }
    __syncthreads();
    #pragma unroll
    for (int i = 0; i < 2; ++i)
        #pragma unroll
        for (int j = 0; j < 2; ++j)
            #pragma unroll
            for (int rr = 0; rr < 4; ++rr)
                ts[wm * 32 + i * 16 + (lane >> 4) * 4 + rr][wn * 32 + j * 16 + (lane & 15)] = acc[i][j][rr];
    __syncthreads();
    const int o = tid >> 2, dofs = (tid & 3) * 16;
    float* op = outP + ((size_t)b * OSo + o) * Dd + d0 + dofs;
    #pragma unroll
    for (int w = 0; w < 4; ++w)
        *(float4*)&op[w * 4] = *(float4*)&ts[o][dofs + w * 4];
}

// ---------------------------------------------------------------------------
// k4: Xh = bf16(relu(BN((XpP0+XpP1)@h_w + h_b)))  tile 64x64, dbuf+prefetch
// ---------------------------------------------------------------------------
struct R4 { float4 p[8]; s8v w[2]; };

__global__ __launch_bounds__(256) void k4(const float* __restrict__ XpP,
                                          const short* __restrict__ h_wT,
                                          const float* __restrict__ h_b,
                                          const float* __restrict__ gamma,
                                          const float* __restrict__ beta,
                                          const float* __restrict__ mean,
                                          const float* __restrict__ var,
                                          short* __restrict__ Xh) {
    __shared__ __align__(16) char smem[32768];
    short* tsb = (short*)smem;                              // epilogue alias [64][64]
    const int tid = threadIdx.x, lane = tid & 63, wave = tid >> 6;
    const int wm = wave >> 1, wn = wave & 1;
    const int h0 = blockIdx.x * 64, m0 = blockIdx.y * 64;
    const int r = tid >> 2, kofs = (tid & 3) * 16;
    const size_t ZS = (size_t)Bb * OSo * Dd;
    f32x4 acc[2][2] = {};
    R4 cur, nxt;
    #pragma unroll
    for (int w = 0; w < 2; ++w) {
        const float* p0 = XpP + (size_t)(m0 + r) * Dd + kofs + w * 8;
        cur.p[w*4+0] = *(const float4*)&p0[0];
        cur.p[w*4+1] = *(const float4*)&p0[4];
        cur.p[w*4+2] = *(const float4*)&p0[ZS];
        cur.p[w*4+3] = *(const float4*)&p0[ZS + 4];
        cur.w[w]     = *(const s8v*)&h_wT[(size_t)(h0 + r) * Dd + kofs + w * 8];
    }
    #pragma unroll
    for (int t = 0; t < 16; ++t) {
        short* As = (short*)(smem + (t & 1) * 8192);
        short* Bs = (short*)(smem + 16384 + (t & 1) * 8192);
        #pragma unroll
        for (int w = 0; w < 2; ++w) {
            const float* f0 = (const float*)&cur.p[w*4];    // 8 f32 from part0
            const float* f1 = (const float*)&cur.p[w*4+2];  // 8 f32 from part1
            s8v s;
            #pragma unroll
            for (int e = 0; e < 8; ++e) s[e] = f2b(f0[e] + f1[e]);
            *(s8v*)&As[swi(r, kofs + w * 8)] = s;
            *(s8v*)&Bs[swi(r, kofs + w * 8)] = cur.w[w];
        }
        __syncthreads();
        if (t < 15) {
            const int k0 = (t + 1) * 64;
            #pragma unroll
            for (int w = 0; w < 2; ++w) {
                const float* p0 = XpP + (size_t)(m0 + r) * Dd + k0 + kofs + w * 8;
                nxt.p[w*4+0] = *(const float4*)&p0[0];
                nxt.p[w*4+1] = *(const float4*)&p0[4];
                nxt.p[w*4+2] = *(const float4*)&p0[ZS];
                nxt.p[w*4+3] = *(const float4*)&p0[ZS + 4];
                nxt.w[w]     = *(const s8v*)&h_wT[(size_t)(h0 + r) * Dd + k0 + kofs + w * 8];
            }
        }
        #pragma unroll
        for (int kk = 0; kk < 2; ++kk) {
            const int kb = kk * 32 + (lane >> 4) * 8;
            s8v a[2], bb[2];
            #pragma unroll
            for (int i = 0; i < 2; ++i)
                a[i] = *(const s8v*)&As[swi(wm * 32 + i * 16 + (lane & 15), kb)];
            #pragma unroll
            for (int j = 0; j < 2; ++j)
                bb[j] = *(const s8v*)&Bs[swi(wn * 32 + j * 16 + (lane & 15), kb)];
            #pragma unroll
            for (int i = 0; i < 2; ++i)
                #pragma unroll
                for (int j = 0; j < 2; ++j)
                    acc[i][j] = MF(a[i], bb[j], acc[i][j]);
        }
        if (t < 15) cur = nxt;
    }
    __syncthreads();
    #pragma unroll
    for (int j = 0; j < 2; ++j) {
        const int h = h0 + wn * 32 + j * 16 + (lane & 15);
        const float sc = gamma[h] * rsqrtf(var[h] + BN_EPS);
        const float of = (h_b[h] - mean[h]) * sc + beta[h];
        #pragma unroll
        for (int i = 0; i < 2; ++i)
            #pragma unroll
            for (int rr = 0; rr < 4; ++rr) {
                const int ml = wm * 32 + i * 16 + (lane >> 4) * 4 + rr;
                tsb[ml * 64 + wn * 32 + j * 16 + (lane & 15)] = f2b(fmaxf(0.f, acc[i][j][rr] * sc + of));
            }
    }
    __syncthreads();
    #pragma unroll
    for (int w = 0; w < 2; ++w)
        *(s8v*)&Xh[(size_t)(m0 + r) * LABh + h0 + kofs + w * 8] = *(const s8v*)&tsb[r * 64 + kofs + w * 8];
}

// ---------------------------------------------------------------------------
// k5: scP[z][b][c][o] partial over K range z.  tile 64(c)x64(o), split-K=4,
// dbuf+prefetch.  grid (16, 16): x = ct(0..3) + 4*z(0..3).
// ---------------------------------------------------------------------------
struct R5 { float4 ld[4]; s8v xh[2]; };

__global__ __launch_bounds__(256) void k5(const int* __restrict__ cand,
                                          const float* __restrict__ labD,
                                          const short* __restrict__ Xh,
                                          float* __restrict__ scP) {
    __shared__ __align__(16) char smem[33024];
    float (*ts)[68] = (float(*)[68])smem;
    int* cidx = (int*)(smem + 32768);
    const int tid = threadIdx.x, lane = tid & 63, wave = tid >> 6;
    const int wm = wave >> 1, wn = wave & 1;
    const int b = blockIdx.y;
    const int ct = blockIdx.x & 3, z = blockIdx.x >> 2;
    const int c0 = ct * 64;
    const int kbase = z * 256;
    if (tid < 64) cidx[tid] = cand[b * NCc + c0 + tid];
    __syncthreads();
    const int r = tid >> 2, kofs = (tid & 3) * 16;
    const int ci = cidx[r];
    const float* lrow = labD + (size_t)ci * LABh + kbase;
    const short* xrow = Xh + (size_t)(b * OSo + r) * LABh + kbase;
    f32x4 acc[2][2] = {};
    R5 cur, nxt;
    #pragma unroll
    for (int w = 0; w < 2; ++w) {
        cur.ld[2*w]   = *(const float4*)&lrow[kofs + w * 8];
        cur.ld[2*w+1] = *(const float4*)&lrow[kofs + w * 8 + 4];
        cur.xh[w]     = *(const s8v*)&xrow[kofs + w * 8];
    }
    #pragma unroll
    for (int t = 0; t < 4; ++t) {
        short* As = (short*)(smem + (t & 1) * 8192);
        short* Bs = (short*)(smem + 16384 + (t & 1) * 8192);
        #pragma unroll
        for (int w = 0; w < 2; ++w) {
            const float* f0 = (const float*)&cur.ld[2*w];
            s8v s;
            #pragma unroll
            for (int e = 0; e < 8; ++e) s[e] = f2b(f0[e]);
            *(s8v*)&As[swi(r, kofs + w * 8)] = s;
            *(s8v*)&Bs[swi(r, kofs + w * 8)] = cur.xh[w];
        }
        __syncthreads();
        if (t < 3) {
            const int k0 = (t + 1) * 64;
            #pragma unroll
            for (int w = 0; w < 2; ++w) {
                cur.ld[2*w];  // keep naming clear; loads below
                nxt.ld[2*w]   = *(const float4*)&lrow[k0 + kofs + w * 8];
                nxt.ld[2*w+1] = *(const float4*)&lrow[k0 + kofs + w * 8 + 4];
                nxt.xh[w]     = *(const s8v*)&xrow[k0 + kofs + w * 8];
            }
        }
        #pragma unroll
        for (int kk = 0; kk < 2; ++kk) {
            const int kb = kk * 32 + (lane >> 4) * 8;
            s8v a[2], bb[2];
            #pragma unroll
            for (int i = 0; i < 2; ++i)
                a[i] = *(const s8v*)&As[swi(wm * 32 + i * 16 + (lane & 15), kb)];
            #pragma unroll
            for (int j = 0; j < 2; ++j)
                bb[j] = *(const s8v*)&Bs[swi(wn * 32 + j * 16 + (lane & 15), kb)];
            #pragma unroll
            for (int i = 0; i < 2; ++i)
                #pragma unroll
                for (int j = 0; j < 2; ++j)
                    acc[i][j] = MF(a[i], bb[j], acc[i][j]);
        }
        if (t < 3) cur = nxt;
    }
    __syncthreads();
    #pragma unroll
    for (int i = 0; i < 2; ++i)
        #pragma unroll
        for (int j = 0; j < 2; ++j)
            #pragma unroll
            for (int rr = 0; rr < 4; ++rr)
                ts[wm * 32 + i * 16 + (lane >> 4) * 4 + rr][wn * 32 + j * 16 + (lane & 15)] = acc[i][j][rr];
    __syncthreads();
    const int oofs = (tid & 3) * 16;
    float* sp = scP + (size_t)z * ((size_t)Bb * NCc * OSo)
                    + ((size_t)b * NCc + c0 + r) * OSo + oofs;
    #pragma unroll
    for (int w = 0; w < 4; ++w)
        *(float4*)&sp[w * 4] = *(float4*)&ts[r][oofs + w * 4];
}

// ---------------------------------------------------------------------------
// k6: sum split-K partials of sc, softmax over o, out = alpha2^T @ Xh
// ---------------------------------------------------------------------------
__global__ __launch_bounds__(256) void k6(const float* __restrict__ scP,
                                          const short* __restrict__ Xh,
                                          float* __restrict__ out) {
    __shared__ float al[16][64];
    const int tid = threadIdx.x;
    const int id = blockIdx.x;
    const int b = (id & 7) * 2 + ((id >> 3) >> 4);
    const int c0 = ((id >> 3) & 15) * 16;
    const size_t ZS = (size_t)Bb * NCc * OSo;
    {
        const int cl = tid >> 4, t16 = tid & 15;
        const float* srow = scP + ((size_t)b * NCc + c0 + cl) * OSo;
        float v[4];
        float m = -1e30f;
        #pragma unroll
        for (int j = 0; j < 4; ++j) {
            v[j] = srow[t16 + j * 16] + srow[ZS + t16 + j * 16]
                 + srow[2 * ZS + t16 + j * 16] + srow[3 * ZS + t16 + j * 16];
            m = fmaxf(m, v[j]);
        }
        #pragma unroll
        for (int off = 8; off; off >>= 1) m = fmaxf(m, __shfl_xor(m, off, 16));
        float s = 0.f;
        #pragma unroll
        for (int j = 0; j < 4; ++j) { v[j] = __expf(v[j] - m); s += v[j]; }
        #pragma unroll
        for (int off = 8; off; off >>= 1) s += __shfl_xor(s, off, 16);
        float inv = 1.f / s;
        #pragma unroll
        for (int j = 0; j < 4; ++j) al[cl][t16 + j * 16] = v[j] * inv;
    }
    __syncthreads();
    const short* xb = Xh + (size_t)b * OSo * LABh;
    float acc[16][4] = {};
    for (int o = 0; o < OSo; ++o) {
        s4v xv = *(const s4v*)&xb[(size_t)o * LABh + tid * 4];
        const float x0 = b2f(xv[0]), x1 = b2f(xv[1]), x2 = b2f(xv[2]), x3 = b2f(xv[3]);
        #pragma unroll
        for (int c = 0; c < 16; ++c) {
            const float w = al[c][o];
            acc[c][0] += w * x0; acc[c][1] += w * x1; acc[c][2] += w * x2; acc[c][3] += w * x3;
        }
    }
    #pragma unroll
    for (int c = 0; c < 16; ++c) {
        float4 v; v.x = acc[c][0]; v.y = acc[c][1]; v.z = acc[c][2]; v.w = acc[c][3];
        *(float4*)&out[((size_t)b * NCc + c0 + c) * LABh + tid * 4] = v;
    }
}

// ---------------------------------------------------------------------------
extern "C" void kernel_launch(void* const* d_in, const int* in_sizes, int n_in,
                              void* d_out, int out_size, void* d_ws, size_t ws_size,
                              hipStream_t stream) {
    (void)in_sizes; (void)n_in; (void)out_size; (void)ws_size;
    const float* X      = (const float*)d_in[0];
    const int*   cand   = (const int*)  d_in[1];
    const float* a_w    = (const float*)d_in[2];
    const float* a_b    = (const float*)d_in[3];
    const float* h_w    = (const float*)d_in[4];
    const float* h_b    = (const float*)d_in[5];
    const float* gamma  = (const float*)d_in[6];
    const float* beta   = (const float*)d_in[7];
    const float* mean   = (const float*)d_in[8];
    const float* var    = (const float*)d_in[9];
    const float* labDesc= (const float*)d_in[10];
    float* outp = (float*)d_out;

    char* ws = (char*)d_ws;
    float* St   = (float*)ws;                               // 8MB: St (k1/k2) then XpP (k3, 2x4MB)
    float* XpP  = St;
    short* aBf  = (short*)(ws + ((size_t)8  << 20));        // 4MB alpha bf16
    short* Xh   = (short*)(ws + ((size_t)12 << 20));        // 2MB
    float* scP  = (float*)(ws + ((size_t)14 << 20));        // 4MB (4 split-K partials)
    short* a_wT = (short*)(ws + ((size_t)18 << 20));        // 128KB
    short* h_wT = (short*)(ws + ((size_t)19 << 20));        // 2MB

    k0 <<<272,          256, 0, stream>>>(h_w, a_w, h_wT, a_wT);
    k1 <<<dim3(32, 16), 256, 0, stream>>>(X, a_wT, a_b, St);
    k2 <<<Bb * OSo,     256, 0, stream>>>(St, aBf);
    k3 <<<512,          256, 0, stream>>>(X, aBf, XpP);
    k4 <<<dim3(16, 16), 256, 0, stream>>>(XpP, h_wT, h_b, gamma, beta, mean, var, Xh);
    k5 <<<dim3(16, 16), 256, 0, stream>>>(cand, labDesc, Xh, scP);
    k6 <<<256,          256, 0, stream>>>(scP, Xh, outp);
}